// Round 17
// baseline (50.040 us; speedup 1.0000x reference)
//
#include <hip/hip_runtime.h>

// Problem constants (from reference)
constexpr int COLS    = 8;
constexpr int BATCH   = 8192;
constexpr int D       = 128;
constexpr int NUM_EMB = 12;
constexpr int NPAIRS  = 28;

constexpr int CHUNKS         = 64;               // row-chunks per pair
constexpr int ROWS_PER_CHUNK = BATCH / CHUNKS;   // 128
constexpr size_t HSTRIDE = (size_t)BATCH * D;    // noise stride between halves

typedef float floatx4 __attribute__((ext_vector_type(4)));

__device__ const int PI_d[NPAIRS] = {0,0,0,0,0,0,0, 1,1,1,1,1,1, 2,2,2,2,2, 3,3,3,3, 4,4,4, 5,5, 6};
__device__ const int PJ_d[NPAIRS] = {1,2,3,4,5,6,7, 2,3,4,5,6,7, 3,4,5,6,7, 4,5,6,7, 5,6,7, 6,7, 7};

__device__ __forceinline__ floatx4 ld4(const float* p) {
    return *reinterpret_cast<const floatx4*>(p);
}
__device__ __forceinline__ void st4(float* p, floatx4 v) {
    *reinterpret_cast<floatx4*>(p) = v;
}
__device__ __forceinline__ float dot4(floatx4 a, floatx4 b) {
    return fmaf(a.x, b.x, fmaf(a.y, b.y, fmaf(a.z, b.z, a.w * b.w)));
}
__device__ __forceinline__ floatx4 vmax4(floatx4 a, floatx4 b) {
    floatx4 r; r.x=fmaxf(a.x,b.x); r.y=fmaxf(a.y,b.y); r.z=fmaxf(a.z,b.z); r.w=fmaxf(a.w,b.w); return r;
}
__device__ __forceinline__ floatx4 vmin4(floatx4 a, floatx4 b) {
    floatx4 r; r.x=fminf(a.x,b.x); r.y=fminf(a.y,b.y); r.z=fminf(a.z,b.z); r.w=fminf(a.w,b.w); return r;
}
__device__ __forceinline__ float softplus01(float x) {
    return 0.01f * ((x > 15.0f) ? x : log1pf(expf(x)));
}

// ===== Row loop, specialized per op S (block-uniform -> hoisted branch) =====
template<int S, bool ATOMIC>
__device__ __forceinline__ void row_loop(
    int k, int chunk, int halfid, int lane, int d0,
    const int* __restrict__ fI, const int* __restrict__ fJ,
    const float* __restrict__ miB, const float* __restrict__ mjB,
    const float* spI, const float* spJ,              // LDS, + d0 applied
    const float* __restrict__ nk0, const float* __restrict__ nk1,
    floatx4 A0, floatx4 B0, floatx4 A1, floatx4 B1,
    float* __restrict__ dst)
{
    #pragma unroll 4
    for (int r = 0; r < ROWS_PER_CHUNK / 8; ++r) {   // 8 rows per iteration
        const int b = chunk * ROWS_PER_CHUNK + r * 8 + halfid;

        // HBM stream (contiguous across the block): the long-latency loads.
        const floatx4 n0 = ld4(nk0 + (size_t)b * D);
        const floatx4 n1 = ld4(nk1 + (size_t)b * D);

        // Small gathers: features (L1), mean (L1/L2), softplus-std (LDS).
        const int fi = fI[b];
        const int fj = fJ[b];
        const floatx4 Mi = ld4(miB + fi * D);
        const floatx4 Mj = ld4(mjB + fj * D);
        const floatx4 Si = ld4(spI + fi * D);
        const floatx4 Sj = ld4(spJ + fj * D);

        const floatx4 p = Mi + Si * n0;   // S' pre-scaled by 0.01
        const floatx4 q = Mj + Sj * n1;

        float a0, a1;
        if constexpr (S == 4) {
            a0 = dot4(p, A0) + dot4(q, B0);
            a1 = dot4(p, A1) + dot4(q, B1);
        } else {
            floatx4 c;
            if constexpr (S == 0)      c = p + q;
            else if constexpr (S == 1) c = p * q;
            else if constexpr (S == 2) c = vmax4(p, q);
            else                       c = vmin4(p, q);
            a0 = dot4(c, A0);
            a1 = dot4(c, A1);
        }

        #pragma unroll
        for (int m = 16; m >= 1; m >>= 1) {
            a0 += __shfl_xor(a0, m, 64);
            a1 += __shfl_xor(a1, m, 64);
        }

        if (lane == 0) {
            if constexpr (ATOMIC) {
                atomicAdd(dst + b * 2 + 0, a0);
                atomicAdd(dst + b * 2 + 1, a1);
            } else {
                float2 r2; r2.x = a0; r2.y = a1;
                *reinterpret_cast<float2*>(dst + ((size_t)k * BATCH + b) * 2) = r2;
            }
        }
    }
}

// ===== Pair-major kernel: one (pair, row-chunk) per block =====
// Softplus fused: each block computes 0.01*softplus(emb_std) for its 2
// columns into LDS (12.3 KB) before the row loop. No other LDS use.
template<bool ATOMIC>
__global__ __launch_bounds__(256) void pair_kernel(
    const int*   __restrict__ features,   // [COLS, BATCH]
    const float* __restrict__ emb_mean,   // [COLS, NUM_EMB, D]
    const float* __restrict__ emb_std,    // [COLS, NUM_EMB, D]
    const float* __restrict__ W_nc,       // [NPAIRS, 4, 2, D]
    const float* __restrict__ W_cat,      // [NPAIRS, 2, 2*D]
    const float* __restrict__ log_alpha,  // [NPAIRS, 5]
    const float* __restrict__ noise,      // [NPAIRS, 2, BATCH, D]
    float*       __restrict__ dst)        // partial [NPAIRS][BATCH][2] or out [BATCH][2]
{
    __shared__ float spS[2][NUM_EMB][D];  // 12,288 B

    const int bid    = blockIdx.x;
    const int k      = bid / CHUNKS;
    const int chunk  = bid % CHUNKS;
    const int tid    = threadIdx.x;
    const int halfid = tid >> 5;           // 0..7: row within the 8-row iter
    const int lane   = tid & 31;
    const int d0     = lane * 4;

    const int i = PI_d[k];
    const int j = PJ_d[k];

    // Stage 0.01*softplus(emb_std) for cols i,j into LDS: 768 f4, 3/thread.
    #pragma unroll
    for (int r = 0; r < 3; ++r) {
        const int idx  = tid + r * 256;          // f4 slot 0..767
        const int col  = idx >= 384 ? 1 : 0;     // 384 f4 per column
        const int rem  = idx - col * 384;        // FIX: 384 is not a pow2; & 383 was wrong
        const int e    = rem >> 5;               // 32 f4 per emb row
        const int dd   = (rem & 31) * 4;
        const int cidx = col ? j : i;
        const floatx4 v = ld4(emb_std + ((size_t)(cidx * NUM_EMB + e)) * D + dd);
        floatx4 o;
        o.x = softplus01(v.x);
        o.y = softplus01(v.y);
        o.z = softplus01(v.z);
        o.w = softplus01(v.w);
        st4(&spS[col][e][dd], o);
    }

    // Routing: argmax over 5 (block-uniform; first-max wins)
    const float* la = log_alpha + k * 5;
    float best = la[0];
    int   s    = 0;
    #pragma unroll
    for (int t = 1; t < 5; ++t) {
        const float v = la[t];
        if (v > best) { best = v; s = t; }
    }

    // Selected weight rows into registers (block-uniform rows, per-lane d0).
    floatx4 A0 = {0,0,0,0}, B0 = {0,0,0,0}, A1 = {0,0,0,0}, B1 = {0,0,0,0};
    if (s == 4) {
        const float* wb = W_cat + (size_t)k * 512;
        A0 = ld4(wb + d0);       B0 = ld4(wb + 128 + d0);
        A1 = ld4(wb + 256 + d0); B1 = ld4(wb + 384 + d0);
    } else {
        const float* wb = W_nc + (size_t)(k * 4 + s) * 256;
        A0 = ld4(wb + d0);
        A1 = ld4(wb + 128 + d0);
    }

    __syncthreads();

    const int* fI = features + i * BATCH;
    const int* fJ = features + j * BATCH;
    const float* miB = emb_mean + (size_t)i * NUM_EMB * D + d0;
    const float* mjB = emb_mean + (size_t)j * NUM_EMB * D + d0;
    const float* spI = &spS[0][0][0] + d0;
    const float* spJ = &spS[1][0][0] + d0;
    const float* nk0 = noise + (size_t)(2 * k) * HSTRIDE + d0;
    const float* nk1 = nk0 + HSTRIDE;

    switch (s) {
        case 0: row_loop<0,ATOMIC>(k,chunk,halfid,lane,d0,fI,fJ,miB,mjB,spI,spJ,nk0,nk1,A0,B0,A1,B1,dst); break;
        case 1: row_loop<1,ATOMIC>(k,chunk,halfid,lane,d0,fI,fJ,miB,mjB,spI,spJ,nk0,nk1,A0,B0,A1,B1,dst); break;
        case 2: row_loop<2,ATOMIC>(k,chunk,halfid,lane,d0,fI,fJ,miB,mjB,spI,spJ,nk0,nk1,A0,B0,A1,B1,dst); break;
        case 3: row_loop<3,ATOMIC>(k,chunk,halfid,lane,d0,fI,fJ,miB,mjB,spI,spJ,nk0,nk1,A0,B0,A1,B1,dst); break;
        default:row_loop<4,ATOMIC>(k,chunk,halfid,lane,d0,fI,fJ,miB,mjB,spI,spJ,nk0,nk1,A0,B0,A1,B1,dst); break;
    }
}

// ===== Deterministic fixed-order reduction over pairs =====
__global__ __launch_bounds__(256) void reduce_kernel(const float* __restrict__ partial,
                                                     float* __restrict__ out)
{
    const int idx = blockIdx.x * 256 + threadIdx.x;   // 0..16383
    float s = 0.0f;
    #pragma unroll
    for (int k = 0; k < NPAIRS; ++k) {
        s += partial[(size_t)k * (BATCH * 2) + idx];
    }
    out[idx] = s;
}

// ===== Fallback: zero out before atomic accumulation =====
__global__ __launch_bounds__(256) void zero_kernel(float* __restrict__ out)
{
    const int idx = blockIdx.x * 256 + threadIdx.x;
    out[idx] = 0.0f;
}

extern "C" void kernel_launch(void* const* d_in, const int* in_sizes, int n_in,
                              void* d_out, int out_size, void* d_ws, size_t ws_size,
                              hipStream_t stream) {
    const int*   features  = (const int*)  d_in[0];
    const float* emb_mean  = (const float*)d_in[1];
    const float* emb_std   = (const float*)d_in[2];
    const float* W_nc      = (const float*)d_in[3];
    const float* W_cat     = (const float*)d_in[4];
    const float* log_alpha = (const float*)d_in[5];
    const float* noise     = (const float*)d_in[6];
    float*       out       = (float*)d_out;

    float* partial = (float*)d_ws;                       // 28*8192*2 floats
    const size_t need_bytes = (size_t)NPAIRS * BATCH * 2 * 4;

    if (ws_size >= need_bytes) {
        pair_kernel<false><<<dim3(NPAIRS * CHUNKS), dim3(256), 0, stream>>>(
            features, emb_mean, emb_std, W_nc, W_cat, log_alpha, noise, partial);
        reduce_kernel<<<dim3(BATCH * 2 / 256), dim3(256), 0, stream>>>(partial, out);
    } else {
        zero_kernel<<<dim3(BATCH * 2 / 256), dim3(256), 0, stream>>>(out);
        pair_kernel<true><<<dim3(NPAIRS * CHUNKS), dim3(256), 0, stream>>>(
            features, emb_mean, emb_std, W_nc, W_cat, log_alpha, noise, out);
    }
}

// Round 18
// 48.150 us; speedup vs baseline: 1.0393x; 1.0393x over previous
//
#include <hip/hip_runtime.h>

// Problem constants (from reference)
constexpr int COLS    = 8;
constexpr int BATCH   = 8192;
constexpr int D       = 128;
constexpr int NUM_EMB = 12;
constexpr int NPAIRS  = 28;

constexpr int CHUNKS         = 64;               // row-chunks per pair
constexpr int ROWS_PER_CHUNK = BATCH / CHUNKS;   // 128
constexpr size_t HSTRIDE = (size_t)BATCH * D;    // noise stride between halves

typedef float floatx4 __attribute__((ext_vector_type(4)));

__device__ const int PI_d[NPAIRS] = {0,0,0,0,0,0,0, 1,1,1,1,1,1, 2,2,2,2,2, 3,3,3,3, 4,4,4, 5,5, 6};
__device__ const int PJ_d[NPAIRS] = {1,2,3,4,5,6,7, 2,3,4,5,6,7, 3,4,5,6,7, 4,5,6,7, 5,6,7, 6,7, 7};

__device__ __forceinline__ floatx4 ld4(const float* p) {
    return *reinterpret_cast<const floatx4*>(p);
}
__device__ __forceinline__ void st4(float* p, floatx4 v) {
    *reinterpret_cast<floatx4*>(p) = v;
}
__device__ __forceinline__ float dot4(floatx4 a, floatx4 b) {
    return fmaf(a.x, b.x, fmaf(a.y, b.y, fmaf(a.z, b.z, a.w * b.w)));
}
__device__ __forceinline__ floatx4 vmax4(floatx4 a, floatx4 b) {
    floatx4 r; r.x=fmaxf(a.x,b.x); r.y=fmaxf(a.y,b.y); r.z=fmaxf(a.z,b.z); r.w=fmaxf(a.w,b.w); return r;
}
__device__ __forceinline__ floatx4 vmin4(floatx4 a, floatx4 b) {
    floatx4 r; r.x=fminf(a.x,b.x); r.y=fminf(a.y,b.y); r.z=fminf(a.z,b.z); r.w=fminf(a.w,b.w); return r;
}
__device__ __forceinline__ float softplus01(float x) {
    return 0.01f * ((x > 15.0f) ? x : log1pf(expf(x)));
}

// ===== Row loop, specialized per op S (block-uniform -> hoisted branch) =====
// In-loop VMEM: ONLY the 2 noise stream loads + 2 feature dwords.
// M and S' come from LDS (2-way bank aliasing = free).
template<int S, bool ATOMIC>
__device__ __forceinline__ void row_loop(
    int k, int chunk, int halfid, int lane,
    const int* __restrict__ fI, const int* __restrict__ fJ,
    const float* mI, const float* mJ,        // LDS, + d0 applied
    const float* sI, const float* sJ,        // LDS, + d0 applied
    const float* __restrict__ nk0, const float* __restrict__ nk1,
    floatx4 A0, floatx4 B0, floatx4 A1, floatx4 B1,
    float* __restrict__ dst)
{
    #pragma unroll 4
    for (int r = 0; r < ROWS_PER_CHUNK / 8; ++r) {   // 8 rows per iteration
        const int b = chunk * ROWS_PER_CHUNK + r * 8 + halfid;

        // HBM stream (contiguous across the block): the long-latency loads.
        const floatx4 n0 = ld4(nk0 + (size_t)b * D);
        const floatx4 n1 = ld4(nk1 + (size_t)b * D);

        // Tiny feature loads (L1-resident) + LDS lookups.
        const int fi = fI[b];
        const int fj = fJ[b];
        const floatx4 Mi = ld4(mI + fi * D);
        const floatx4 Mj = ld4(mJ + fj * D);
        const floatx4 Si = ld4(sI + fi * D);
        const floatx4 Sj = ld4(sJ + fj * D);

        const floatx4 p = Mi + Si * n0;   // S' pre-scaled by 0.01
        const floatx4 q = Mj + Sj * n1;

        float a0, a1;
        if constexpr (S == 4) {
            a0 = dot4(p, A0) + dot4(q, B0);
            a1 = dot4(p, A1) + dot4(q, B1);
        } else {
            floatx4 c;
            if constexpr (S == 0)      c = p + q;
            else if constexpr (S == 1) c = p * q;
            else if constexpr (S == 2) c = vmax4(p, q);
            else                       c = vmin4(p, q);
            a0 = dot4(c, A0);
            a1 = dot4(c, A1);
        }

        // Packed dual reduce: xor16 both, select by lane half, xor8/4/2/1.
        a0 += __shfl_xor(a0, 16, 64);
        a1 += __shfl_xor(a1, 16, 64);
        float v = (lane & 16) ? a1 : a0;
        v += __shfl_xor(v, 8, 64);
        v += __shfl_xor(v, 4, 64);
        v += __shfl_xor(v, 2, 64);
        v += __shfl_xor(v, 1, 64);
        // lane 0 holds a0 total, lane 16 holds a1 total.

        if constexpr (ATOMIC) {
            if (lane == 0)  atomicAdd(dst + b * 2 + 0, v);
            if (lane == 16) atomicAdd(dst + b * 2 + 1, v);
        } else {
            if (lane == 0)  dst[((size_t)k * BATCH + b) * 2 + 0] = v;
            if (lane == 16) dst[((size_t)k * BATCH + b) * 2 + 1] = v;
        }
    }
}

// ===== Pair-major kernel: one (pair, row-chunk) per block =====
// Stages BOTH emb_mean and 0.01*softplus(emb_std) for its 2 columns into LDS
// (24.6 KB): kills the 235 MB of per-row M-gather L2 traffic.
template<bool ATOMIC>
__global__ __launch_bounds__(256) void pair_kernel(
    const int*   __restrict__ features,   // [COLS, BATCH]
    const float* __restrict__ emb_mean,   // [COLS, NUM_EMB, D]
    const float* __restrict__ emb_std,    // [COLS, NUM_EMB, D]
    const float* __restrict__ W_nc,       // [NPAIRS, 4, 2, D]
    const float* __restrict__ W_cat,      // [NPAIRS, 2, 2*D]
    const float* __restrict__ log_alpha,  // [NPAIRS, 5]
    const float* __restrict__ noise,      // [NPAIRS, 2, BATCH, D]
    float*       __restrict__ dst)        // partial [NPAIRS][BATCH][2] or out [BATCH][2]
{
    __shared__ float sp[2][2][NUM_EMB][D];  // [M/S][col i/j][emb][d] = 24,576 B

    const int bid    = blockIdx.x;
    const int k      = bid / CHUNKS;
    const int chunk  = bid % CHUNKS;
    const int tid    = threadIdx.x;
    const int halfid = tid >> 5;           // 0..7: row within the 8-row iter
    const int lane   = tid & 31;
    const int d0     = lane * 4;

    const int i = PI_d[k];
    const int j = PJ_d[k];

    // Stage M and 0.01*softplus(S) for cols i,j: 1536 f4 slots, 6/thread.
    #pragma unroll
    for (int r = 0; r < 6; ++r) {
        const int idx = tid + r * 256;          // f4 slot 0..1535
        const int arr = idx >= 768 ? 1 : 0;     // 0 = M, 1 = S
        const int w   = idx - arr * 768;
        const int col = w >= 384 ? 1 : 0;
        const int rem = w - col * 384;          // subtraction, NOT & (384 != pow2)
        const int e   = rem >> 5;               // 32 f4 per emb row
        const int dd  = (rem & 31) * 4;
        const int cidx = col ? j : i;
        const float* src = (arr ? emb_std : emb_mean)
                         + ((size_t)(cidx * NUM_EMB + e)) * D + dd;
        floatx4 v = ld4(src);
        if (arr) {
            v.x = softplus01(v.x);
            v.y = softplus01(v.y);
            v.z = softplus01(v.z);
            v.w = softplus01(v.w);
        }
        st4(&sp[arr][col][e][dd], v);
    }

    // Routing: argmax over 5 (block-uniform; first-max wins)
    const float* la = log_alpha + k * 5;
    float best = la[0];
    int   s    = 0;
    #pragma unroll
    for (int t = 1; t < 5; ++t) {
        const float v = la[t];
        if (v > best) { best = v; s = t; }
    }

    // Selected weight rows into registers (block-uniform rows, per-lane d0).
    floatx4 A0 = {0,0,0,0}, B0 = {0,0,0,0}, A1 = {0,0,0,0}, B1 = {0,0,0,0};
    if (s == 4) {
        const float* wb = W_cat + (size_t)k * 512;
        A0 = ld4(wb + d0);       B0 = ld4(wb + 128 + d0);
        A1 = ld4(wb + 256 + d0); B1 = ld4(wb + 384 + d0);
    } else {
        const float* wb = W_nc + (size_t)(k * 4 + s) * 256;
        A0 = ld4(wb + d0);
        A1 = ld4(wb + 128 + d0);
    }

    __syncthreads();

    const int* fI = features + i * BATCH;
    const int* fJ = features + j * BATCH;
    const float* mI = &sp[0][0][0][0] + d0;
    const float* mJ = &sp[0][1][0][0] + d0;
    const float* sI = &sp[1][0][0][0] + d0;
    const float* sJ = &sp[1][1][0][0] + d0;
    const float* nk0 = noise + (size_t)(2 * k) * HSTRIDE + d0;
    const float* nk1 = nk0 + HSTRIDE;

    switch (s) {
        case 0: row_loop<0,ATOMIC>(k,chunk,halfid,lane,fI,fJ,mI,mJ,sI,sJ,nk0,nk1,A0,B0,A1,B1,dst); break;
        case 1: row_loop<1,ATOMIC>(k,chunk,halfid,lane,fI,fJ,mI,mJ,sI,sJ,nk0,nk1,A0,B0,A1,B1,dst); break;
        case 2: row_loop<2,ATOMIC>(k,chunk,halfid,lane,fI,fJ,mI,mJ,sI,sJ,nk0,nk1,A0,B0,A1,B1,dst); break;
        case 3: row_loop<3,ATOMIC>(k,chunk,halfid,lane,fI,fJ,mI,mJ,sI,sJ,nk0,nk1,A0,B0,A1,B1,dst); break;
        default:row_loop<4,ATOMIC>(k,chunk,halfid,lane,fI,fJ,mI,mJ,sI,sJ,nk0,nk1,A0,B0,A1,B1,dst); break;
    }
}

// ===== Deterministic fixed-order reduction over pairs =====
__global__ __launch_bounds__(256) void reduce_kernel(const float* __restrict__ partial,
                                                     float* __restrict__ out)
{
    const int idx = blockIdx.x * 256 + threadIdx.x;   // 0..16383
    float s = 0.0f;
    #pragma unroll
    for (int k = 0; k < NPAIRS; ++k) {
        s += partial[(size_t)k * (BATCH * 2) + idx];
    }
    out[idx] = s;
}

// ===== Fallback: zero out before atomic accumulation =====
__global__ __launch_bounds__(256) void zero_kernel(float* __restrict__ out)
{
    const int idx = blockIdx.x * 256 + threadIdx.x;
    out[idx] = 0.0f;
}

extern "C" void kernel_launch(void* const* d_in, const int* in_sizes, int n_in,
                              void* d_out, int out_size, void* d_ws, size_t ws_size,
                              hipStream_t stream) {
    const int*   features  = (const int*)  d_in[0];
    const float* emb_mean  = (const float*)d_in[1];
    const float* emb_std   = (const float*)d_in[2];
    const float* W_nc      = (const float*)d_in[3];
    const float* W_cat     = (const float*)d_in[4];
    const float* log_alpha = (const float*)d_in[5];
    const float* noise     = (const float*)d_in[6];
    float*       out       = (float*)d_out;

    float* partial = (float*)d_ws;                       // 28*8192*2 floats
    const size_t need_bytes = (size_t)NPAIRS * BATCH * 2 * 4;

    if (ws_size >= need_bytes) {
        pair_kernel<false><<<dim3(NPAIRS * CHUNKS), dim3(256), 0, stream>>>(
            features, emb_mean, emb_std, W_nc, W_cat, log_alpha, noise, partial);
        reduce_kernel<<<dim3(BATCH * 2 / 256), dim3(256), 0, stream>>>(partial, out);
    } else {
        zero_kernel<<<dim3(BATCH * 2 / 256), dim3(256), 0, stream>>>(out);
        pair_kernel<true><<<dim3(NPAIRS * CHUNKS), dim3(256), 0, stream>>>(
            features, emb_mean, emb_std, W_nc, W_cat, log_alpha, noise, out);
    }
}